// Round 5
// baseline (17.830 us; speedup 1.0000x reference)
//
#include <hip/hip_runtime.h>

// Problem constants (B,C,H,W,L) = (4,16,256,256,25)
#define HWPIX 65536   // H*W
#define NCH   16
#define NLBL  25

// Model update (R1-R4 evidence): wide LDS reads (b64/b128) do NOT merge
// duplicate lane addresses -> gathered weight reads cost ~20-34 cyc/instr
// regardless of layout.  Only b32 same-address broadcast is free (m136).
// So: store weights as PACKED BF16 PAIRS, uint w2h[k][l] = (w[l][2k+1],w[l][2k])
// with flat in-matrix index o*16+c -> k = o*8 + c/2.
// Read path: ds_read_b32 at bank l%32; with l < 25 < 32, each bank sees at
// most ONE distinct address per instruction -> pure broadcast, conflict-free
// (~5.8 cyc/instr throughput).  128 reads/px instead of 64 conflicted b128s.
// bf16 weights: absmax err ~0.02 << 0.143 threshold.

__device__ __forceinline__ unsigned int pack_bf16_rtn(float lo, float hi) {
    unsigned int ul = __float_as_uint(lo);
    unsigned int uh = __float_as_uint(hi);
    ul += 0x7FFFu + ((ul >> 16) & 1u);   // round-to-nearest-even
    uh += 0x7FFFu + ((uh >> 16) & 1u);
    return (ul >> 16) | (uh & 0xFFFF0000u);
}

__global__ __launch_bounds__(256) void invconv_kernel(
    const float* __restrict__ x,
    const int*   __restrict__ labels,
    const float* __restrict__ weight,
    const float* __restrict__ bias,
    float*       __restrict__ out)
{
    __shared__ unsigned int w2h[128][32];   // 16 KiB

    const int tid = threadIdx.x;

    // One pixel per thread: 1024 blocks x 256 thr = 16 waves/CU.
    const int t = blockIdx.x * 256 + tid;
    const int b = t >> 16;               // / HWPIX
    const int p = t & 65535;             // % HWPIX

    // Issue label + x loads BEFORE staging so HBM latency overlaps it.
    const int l0 = labels[b * HWPIX + p];

    float xv[NCH];
    const float* xb = x + b * (NCH * HWPIX) + p;
    #pragma unroll
    for (int c = 0; c < NCH; ++c)
        xv[c] = xb[c * HWPIX];           // 4B/lane, coalesced 256B/wave-instr

    // Stage weights as packed bf16 pairs.  flat = l*128 + k so the global
    // float2 reads are COALESCED (consecutive lanes -> consecutive k, same l).
    // LDS writes: whole wave hits bank l (64-way serialized) but it's a
    // one-time ~300cyc staging cost amortized over 256 px.
    #pragma unroll
    for (int i = 0; i < 13; ++i) {
        int flat = tid + i * 256;        // < 3328; valid slots < 25*128=3200
        if (flat < NLBL * 128) {
            int l = flat >> 7;           // 0..24
            int k = flat & 127;          // 0..127
            const float2 wv = *reinterpret_cast<const float2*>(weight + l * 256 + k * 2);
            w2h[k][l] = pack_bf16_rtn(wv.x, wv.y);
        }
    }
    __syncthreads();

    const float bias0 = bias[l0];

    float* ob = out + b * (NCH * HWPIX) + p;
    #pragma unroll
    for (int o = 0; o < NCH; ++o) {
        float acc0 = bias0;
        #pragma unroll
        for (int k2 = 0; k2 < 8; ++k2) {
            const unsigned int pw = w2h[o * 8 + k2][l0];   // b32 broadcast
            const float wlo = __uint_as_float(pw << 16);
            const float whi = __uint_as_float(pw & 0xFFFF0000u);
            acc0 = fmaf(wlo, xv[2 * k2 + 0], acc0);
            acc0 = fmaf(whi, xv[2 * k2 + 1], acc0);
        }
        ob[o * HWPIX] = acc0;
    }
}

extern "C" void kernel_launch(void* const* d_in, const int* in_sizes, int n_in,
                              void* d_out, int out_size, void* d_ws, size_t ws_size,
                              hipStream_t stream) {
    const float* x      = (const float*)d_in[0];
    const int*   labels = (const int*)  d_in[1];
    const float* weight = (const float*)d_in[2];
    const float* bias   = (const float*)d_in[3];
    float*       out    = (float*)d_out;

    // total pixels = 262144; 1 px/thread, 256 threads/block -> 1024 blocks
    dim3 grid(1024), block(256);
    invconv_kernel<<<grid, block, 0, stream>>>(x, labels, weight, bias, out);
}

// Round 6
// 13.937 us; speedup vs baseline: 1.2793x; 1.2793x over previous
//
#include <hip/hip_runtime.h>

// Problem constants (B,C,H,W,L) = (4,16,256,256,25)
#define HWPIX 65536   // H*W
#define NCH   16
#define NLBL  25

// Model (R1-R5 measured): divergent-address LDS gathers cost ~21-34 cyc/instr
// regardless of width (address-processing limited, ~2-3 divergent addr/cyc).
// So: minimize gather INSTRUCTION COUNT, maximize bytes/instr.
// Weights packed as bf16, 8 per uint4: w8[k][l] = weight[l][8k..8k+7],
// k = o*2 + q (q = c/8).  32 ds_read_b128 per pixel (was 64 in R4).
// bf16 absmax err measured 0.031 (R5) << 0.143 threshold.

__device__ __forceinline__ unsigned int pack_bf16_rtn(float lo, float hi) {
    unsigned int ul = __float_as_uint(lo);
    unsigned int uh = __float_as_uint(hi);
    ul += 0x7FFFu + ((ul >> 16) & 1u);   // round-to-nearest-even
    uh += 0x7FFFu + ((uh >> 16) & 1u);
    return (ul >> 16) | (uh & 0xFFFF0000u);
}

__global__ __launch_bounds__(256) void invconv_kernel(
    const float* __restrict__ x,
    const int*   __restrict__ labels,
    const float* __restrict__ weight,
    const float* __restrict__ bias,
    float*       __restrict__ out)
{
    __shared__ uint4 w8[32][32];   // 16 KiB

    const int tid = threadIdx.x;

    // One pixel per thread: 1024 blocks x 256 thr = 16 waves/CU.
    const int t = blockIdx.x * 256 + tid;
    const int b = t >> 16;               // / HWPIX
    const int p = t & 65535;             // % HWPIX

    // Issue label + x loads BEFORE staging so HBM latency overlaps it.
    const int l0 = labels[b * HWPIX + p];

    float xv[NCH];
    const float* xb = x + b * (NCH * HWPIX) + p;
    #pragma unroll
    for (int c = 0; c < NCH; ++c)
        xv[c] = xb[c * HWPIX];           // 4B/lane, coalesced

    // Stage + pack weights: 25*32 = 800 uint4 slots.
    // f = l*32 + k -> consecutive lanes take consecutive k (same l):
    // global reads at 32-float stride, two float4 each; one-time cost.
    #pragma unroll
    for (int i = 0; i < 4; ++i) {
        int f = tid + i * 256;           // < 1024
        if (f < NLBL * 32) {
            int l = f >> 5;
            int k = f & 31;
            const float* wp = weight + l * 256 + k * 8;
            const float4 a = *reinterpret_cast<const float4*>(wp);
            const float4 c = *reinterpret_cast<const float4*>(wp + 4);
            uint4 pk;
            pk.x = pack_bf16_rtn(a.x, a.y);
            pk.y = pack_bf16_rtn(a.z, a.w);
            pk.z = pack_bf16_rtn(c.x, c.y);
            pk.w = pack_bf16_rtn(c.z, c.w);
            w8[k][l] = pk;
        }
    }
    __syncthreads();

    const float bias0 = bias[l0];

    float* ob = out + b * (NCH * HWPIX) + p;
    #pragma unroll
    for (int o = 0; o < NCH; ++o) {
        const uint4 wa = w8[o * 2 + 0][l0];   // weight[l0][o][0..7]  bf16
        const uint4 wb = w8[o * 2 + 1][l0];   // weight[l0][o][8..15] bf16
        float acc0 = bias0;
        // dword d of wa covers channels (2d, 2d+1); of wb: (8+2d, 8+2d+1)
        acc0 = fmaf(__uint_as_float(wa.x << 16),          xv[0],  acc0);
        acc0 = fmaf(__uint_as_float(wa.x & 0xFFFF0000u),  xv[1],  acc0);
        acc0 = fmaf(__uint_as_float(wa.y << 16),          xv[2],  acc0);
        acc0 = fmaf(__uint_as_float(wa.y & 0xFFFF0000u),  xv[3],  acc0);
        acc0 = fmaf(__uint_as_float(wa.z << 16),          xv[4],  acc0);
        acc0 = fmaf(__uint_as_float(wa.z & 0xFFFF0000u),  xv[5],  acc0);
        acc0 = fmaf(__uint_as_float(wa.w << 16),          xv[6],  acc0);
        acc0 = fmaf(__uint_as_float(wa.w & 0xFFFF0000u),  xv[7],  acc0);
        acc0 = fmaf(__uint_as_float(wb.x << 16),          xv[8],  acc0);
        acc0 = fmaf(__uint_as_float(wb.x & 0xFFFF0000u),  xv[9],  acc0);
        acc0 = fmaf(__uint_as_float(wb.y << 16),          xv[10], acc0);
        acc0 = fmaf(__uint_as_float(wb.y & 0xFFFF0000u),  xv[11], acc0);
        acc0 = fmaf(__uint_as_float(wb.z << 16),          xv[12], acc0);
        acc0 = fmaf(__uint_as_float(wb.z & 0xFFFF0000u),  xv[13], acc0);
        acc0 = fmaf(__uint_as_float(wb.w << 16),          xv[14], acc0);
        acc0 = fmaf(__uint_as_float(wb.w & 0xFFFF0000u),  xv[15], acc0);
        ob[o * HWPIX] = acc0;
    }
}

extern "C" void kernel_launch(void* const* d_in, const int* in_sizes, int n_in,
                              void* d_out, int out_size, void* d_ws, size_t ws_size,
                              hipStream_t stream) {
    const float* x      = (const float*)d_in[0];
    const int*   labels = (const int*)  d_in[1];
    const float* weight = (const float*)d_in[2];
    const float* bias   = (const float*)d_in[3];
    float*       out    = (float*)d_out;

    // total pixels = 262144; 1 px/thread, 256 threads/block -> 1024 blocks
    dim3 grid(1024), block(256);
    invconv_kernel<<<grid, block, 0, stream>>>(x, labels, weight, bias, out);
}